// Round 1
// baseline (760.901 us; speedup 1.0000x reference)
//
#include <hip/hip_runtime.h>

// QRotationCrossAttention on MI355X (gfx950)
// B=4, C=512, Q=4, H=W=64 -> S = Q*H*W = 16384, G = C/4 = 128, heads = 4 (=quaternion comps)
//
// Pipeline (all bf16 storage, fp32 accum):
//  1. transpose-convert x1,x2 -> x1t,x2t bf16 [B][S][C]; convert Wq,Wk,Wa1; WvT; Woh (head-gathered Wo)
//  2. gemm_a1_aw: a1 = relu(Wa1@x1+ba1) fused with a2 = Wa2@a1+ba2, softmax -> aw [B][4][S] fp32
//  3. gemm q = gate(Wq@x1+bq), k = gate(Wk@x2+bk)  (bf16 out, [B][C][S])
//  4. logits L[b,h,g,f] = sum_s q[b,4g+h,s]*k[b,4f+h,s]  (split-K MFMA + atomicAdd fp32)
//  5. softmax(L*scale) -> attnT bf16 [bh][f][g]
//  6. fold: Weff[b][o][4f+h] = sum_g Woh[h][o][g]*attn[g][f]  (MFMA)
//          W2[b] = Weff[b]@Wv (MFMA), b2[b] = Weff[b]@bv + bo
//  7. o2[b] = W2[b]@x2[b] + b2  (bf16, reuses x1t slot)
//  8. IQBN stats per (c,qq) over (b,h,w); normalize -> fp32 out
//
// ws requirement: ~266 MB.

#define DEVI __device__ __forceinline__
typedef unsigned short u16;
typedef __bf16 bf16x8 __attribute__((ext_vector_type(8)));
typedef float f32x4 __attribute__((ext_vector_type(4)));

DEVI float bf2f(unsigned int u) {
  union { unsigned int u; float f; } v; v.u = u << 16; return v.f;
}
DEVI u16 f2bf(float f) {
  union { float f; unsigned int u; } v; v.f = f;
  unsigned int r = v.u + 0x7FFFu + ((v.u >> 16) & 1u);
  return (u16)(r >> 16);
}
DEVI void gload_lds16(const void* gp, void* lp) {
  __builtin_amdgcn_global_load_lds((const __attribute__((address_space(1))) int*)gp,
                                   (__attribute__((address_space(3))) int*)lp, 16, 0, 0);
}

// ---------------- converts ----------------
__global__ __launch_bounds__(256) void cvt_k(const float* __restrict__ in, u16* __restrict__ out, int n4) {
  int i = blockIdx.x * 256 + threadIdx.x;
  if (i < n4) {
    float4 v = reinterpret_cast<const float4*>(in)[i];
    ushort4 o; o.x = f2bf(v.x); o.y = f2bf(v.y); o.z = f2bf(v.z); o.w = f2bf(v.w);
    reinterpret_cast<ushort4*>(out)[i] = o;
  }
}

// in[b][r][c] fp32 -> out[b][c][r] bf16
__global__ __launch_bounds__(256) void transpose_cvt(const float* __restrict__ in, u16* __restrict__ out,
                                                     int R, int Cc, long sIn, long sOut) {
  __shared__ float tile[64][65];
  const int t = threadIdx.x;
  const int c0 = blockIdx.x * 64, r0 = blockIdx.y * 64, b = blockIdx.z;
  const float* ip = in + (long)b * sIn;
  u16* op = out + (long)b * sOut;
#pragma unroll
  for (int i = 0; i < 4; ++i) {
    int r = (t >> 4) + i * 16;
    int c = (t & 15) * 4;
    float4 v = *reinterpret_cast<const float4*>(ip + (long)(r0 + r) * Cc + c0 + c);
    tile[r][c] = v.x; tile[r][c + 1] = v.y; tile[r][c + 2] = v.z; tile[r][c + 3] = v.w;
  }
  __syncthreads();
#pragma unroll
  for (int i = 0; i < 4; ++i) {
    int c = (t >> 4) + i * 16;
    int r = (t & 15) * 4;
    ushort4 o;
    o.x = f2bf(tile[r][c]); o.y = f2bf(tile[r + 1][c]);
    o.z = f2bf(tile[r + 2][c]); o.w = f2bf(tile[r + 3][c]);
    *reinterpret_cast<ushort4*>(op + (long)(c0 + c) * R + r0 + r) = o;
  }
}

// Woh[h][o][g] = bf16(Wo[o][4g+h])
__global__ __launch_bounds__(256) void woh_k(const float* __restrict__ Wo, u16* __restrict__ Woh) {
  int idx = blockIdx.x * 256 + threadIdx.x;  // < 262144
  int h = idx >> 16;
  int o = (idx >> 7) & 511;
  int g = idx & 127;
  union { float f; unsigned int u; } v; v.f = Wo[(long)o * 512 + 4 * g + h];
  unsigned int r = v.u + 0x7FFFu + ((v.u >> 16) & 1u);
  Woh[idx] = (u16)(r >> 16);
}

// ---------------- generic bf16 MFMA GEMM: C[M,N] = A[M,K] @ Bt[N,K]^T ----------------
enum { MODE_GATE = 0, MODE_BIAS = 1, MODE_PLAIN = 2, MODE_FOLD1 = 3 };

template <int MODE>
__global__ __launch_bounds__(256) void gemm_bt(const u16* __restrict__ A, const u16* __restrict__ Bt,
                                               u16* __restrict__ C, const float* __restrict__ bias,
                                               const float* __restrict__ aw, int M, int N, int K,
                                               long sA, long sB, long sC) {
  __shared__ u16 As[128 * 64];
  __shared__ u16 Bs[128 * 64];
  const int t = threadIdx.x;
  const int bn = blockIdx.x, bm = blockIdx.y, bz = blockIdx.z;
  const u16* Ab;
  const u16* Bb;
  if constexpr (MODE == MODE_FOLD1) {
    Ab = A + (long)(bz & 3) * 512 * 128;
    Bb = Bt + (long)bz * 128 * 128;
  } else {
    Ab = A + (long)bz * sA;
    Bb = Bt + (long)bz * sB;
  }
  const u16* Atile = Ab + (long)(bm * 128) * K;
  const u16* Btile = Bb + (long)(bn * 128) * K;
  const int wid = t >> 6, l = t & 63;
  const int rbase = (wid >> 1) * 64, cbase = (wid & 1) * 64;
  const int lr = l & 15, lkb = (l >> 4) * 8, hi = l >> 4;
  f32x4 acc[4][4] = {};
  for (int kt = 0; kt < K; kt += 64) {
#pragma unroll
    for (int i = 0; i < 4; ++i) {
      int idx = t + i * 256;
      int r = idx >> 3, cc = (idx & 7) * 8;
      gload_lds16(Atile + (long)r * K + kt + cc, &As[idx * 8]);
      gload_lds16(Btile + (long)r * K + kt + cc, &Bs[idx * 8]);
    }
    __syncthreads();
#pragma unroll
    for (int s = 0; s < 2; ++s) {
      bf16x8 av[4], bv[4];
#pragma unroll
      for (int m = 0; m < 4; ++m)
        av[m] = *reinterpret_cast<const bf16x8*>(&As[(rbase + m * 16 + lr) * 64 + s * 32 + lkb]);
#pragma unroll
      for (int n = 0; n < 4; ++n)
        bv[n] = *reinterpret_cast<const bf16x8*>(&Bs[(cbase + n * 16 + lr) * 64 + s * 32 + lkb]);
#pragma unroll
      for (int m = 0; m < 4; ++m)
#pragma unroll
        for (int n = 0; n < 4; ++n)
          acc[m][n] = __builtin_amdgcn_mfma_f32_16x16x32_bf16(av[m], bv[n], acc[m][n], 0, 0, 0);
    }
    __syncthreads();
  }
#pragma unroll
  for (int m = 0; m < 4; ++m) {
#pragma unroll
    for (int r = 0; r < 4; ++r) {
      int row = bm * 128 + rbase + m * 16 + hi * 4 + r;
      float bval = 0.f;
      if constexpr (MODE == MODE_GATE) bval = bias[row];
      if constexpr (MODE == MODE_BIAS) bval = bias[bz * M + row];
#pragma unroll
      for (int n = 0; n < 4; ++n) {
        int col = bn * 128 + cbase + n * 16 + lr;
        float v = acc[m][n][r] + bval;
        if constexpr (MODE == MODE_GATE)
          v *= aw[((long)bz * 4 + (row & 3)) * N + col];
        if constexpr (MODE == MODE_FOLD1)
          C[((long)(bz >> 2) * 512 + row) * 512 + 4 * col + (bz & 3)] = f2bf(v);
        else
          C[(long)bz * sC + (long)row * N + col] = f2bf(v);
      }
    }
  }
}

// ---------------- a1 GEMM fused with gate-MLP head + softmax -> aw ----------------
__global__ __launch_bounds__(256) void gemm_a1_aw(const u16* __restrict__ Wa1b, const u16* __restrict__ X1t,
                                                  const float* __restrict__ ba1, const float* __restrict__ Wa2,
                                                  const float* __restrict__ ba2, float* __restrict__ AW) {
  __shared__ union {
    struct { u16 As[128 * 64]; u16 Bs[128 * 64]; } st;
    float a1s[128][129];
  } u;
  __shared__ float wa2s[512];
  const int t = threadIdx.x;
  const int bn = blockIdx.x, bz = blockIdx.z;
  for (int i = t; i < 512; i += 256) wa2s[i] = Wa2[i];
  const u16* Btile = X1t + (long)bz * 16384 * 512 + (long)(bn * 128) * 512;
  const int wid = t >> 6, l = t & 63;
  const int rbase = (wid >> 1) * 64, cbase = (wid & 1) * 64;
  const int lr = l & 15, lkb = (l >> 4) * 8, hi = l >> 4;
  f32x4 acc[4][4] = {};
  for (int kt = 0; kt < 512; kt += 64) {
#pragma unroll
    for (int i = 0; i < 4; ++i) {
      int idx = t + i * 256;
      int r = idx >> 3, cc = (idx & 7) * 8;
      gload_lds16(Wa1b + (long)r * 512 + kt + cc, &u.st.As[idx * 8]);
      gload_lds16(Btile + (long)r * 512 + kt + cc, &u.st.Bs[idx * 8]);
    }
    __syncthreads();
#pragma unroll
    for (int s = 0; s < 2; ++s) {
      bf16x8 av[4], bv[4];
#pragma unroll
      for (int m = 0; m < 4; ++m)
        av[m] = *reinterpret_cast<const bf16x8*>(&u.st.As[(rbase + m * 16 + lr) * 64 + s * 32 + lkb]);
#pragma unroll
      for (int n = 0; n < 4; ++n)
        bv[n] = *reinterpret_cast<const bf16x8*>(&u.st.Bs[(cbase + n * 16 + lr) * 64 + s * 32 + lkb]);
#pragma unroll
      for (int m = 0; m < 4; ++m)
#pragma unroll
        for (int n = 0; n < 4; ++n)
          acc[m][n] = __builtin_amdgcn_mfma_f32_16x16x32_bf16(av[m], bv[n], acc[m][n], 0, 0, 0);
    }
    __syncthreads();
  }
  // stash relu(a1) transposed: a1s[pos][ch]
#pragma unroll
  for (int m = 0; m < 4; ++m) {
#pragma unroll
    for (int r = 0; r < 4; ++r) {
      int row = rbase + m * 16 + hi * 4 + r;
      float bval = ba1[row];
#pragma unroll
      for (int n = 0; n < 4; ++n) {
        int col = cbase + n * 16 + lr;
        float v = acc[m][n][r] + bval;
        u.a1s[col][row] = v > 0.f ? v : 0.f;
      }
    }
  }
  __syncthreads();
  if (t < 128) {
    float a0 = ba2[0], a1 = ba2[1], a2 = ba2[2], a3 = ba2[3];
#pragma unroll 4
    for (int c = 0; c < 128; ++c) {
      float av = u.a1s[t][c];
      a0 += wa2s[c] * av; a1 += wa2s[128 + c] * av;
      a2 += wa2s[256 + c] * av; a3 += wa2s[384 + c] * av;
    }
    float mx = fmaxf(fmaxf(a0, a1), fmaxf(a2, a3));
    float e0 = __expf(a0 - mx), e1 = __expf(a1 - mx), e2 = __expf(a2 - mx), e3 = __expf(a3 - mx);
    float inv = 1.f / (e0 + e1 + e2 + e3);
    long sg = (long)bn * 128 + t;
    float* awp = AW + (long)bz * 4 * 16384;
    awp[sg] = e0 * inv;
    awp[16384 + sg] = e1 * inv;
    awp[2 * 16384 + sg] = e2 * inv;
    awp[3 * 16384 + sg] = e3 * inv;
  }
}

// ---------------- logits: L[bh][g][f] += sum_{s in split} q[b,4g+h,s]*k[b,4f+h,s] ----------------
__global__ __launch_bounds__(256) void logits_k(const u16* __restrict__ Q, const u16* __restrict__ Kt,
                                                float* __restrict__ L) {
  __shared__ u16 As[128 * 64];
  __shared__ u16 Bs[128 * 64];
  const int S = 16384;
  const int ks = blockIdx.x;   // 8 K-splits of 2048
  const int bh = blockIdx.y;   // b*4+h
  const int b = bh >> 2, h = bh & 3;
  const int t = threadIdx.x;
  const int wid = t >> 6, l = t & 63;
  const int rbase = (wid >> 1) * 64, cbase = (wid & 1) * 64;
  const int lr = l & 15, lkb = (l >> 4) * 8, hi = l >> 4;
  const u16* qb = Q + (long)b * 512 * S + (long)h * S;
  const u16* kb = Kt + (long)b * 512 * S + (long)h * S;
  const int k0 = ks * 2048;
  f32x4 acc[4][4] = {};
  for (int kt = 0; kt < 2048; kt += 64) {
    int kk = k0 + kt;
#pragma unroll
    for (int i = 0; i < 4; ++i) {
      int idx = t + i * 256;
      int r = idx >> 3, cc = (idx & 7) * 8;
      gload_lds16(qb + (long)4 * r * S + kk + cc, &As[idx * 8]);
      gload_lds16(kb + (long)4 * r * S + kk + cc, &Bs[idx * 8]);
    }
    __syncthreads();
#pragma unroll
    for (int s = 0; s < 2; ++s) {
      bf16x8 av[4], bv[4];
#pragma unroll
      for (int m = 0; m < 4; ++m)
        av[m] = *reinterpret_cast<const bf16x8*>(&As[(rbase + m * 16 + lr) * 64 + s * 32 + lkb]);
#pragma unroll
      for (int n = 0; n < 4; ++n)
        bv[n] = *reinterpret_cast<const bf16x8*>(&Bs[(cbase + n * 16 + lr) * 64 + s * 32 + lkb]);
#pragma unroll
      for (int m = 0; m < 4; ++m)
#pragma unroll
        for (int n = 0; n < 4; ++n)
          acc[m][n] = __builtin_amdgcn_mfma_f32_16x16x32_bf16(av[m], bv[n], acc[m][n], 0, 0, 0);
    }
    __syncthreads();
  }
  float* Lb = L + (long)bh * 128 * 128;
#pragma unroll
  for (int m = 0; m < 4; ++m)
#pragma unroll
    for (int r = 0; r < 4; ++r) {
      int row = rbase + m * 16 + hi * 4 + r;
#pragma unroll
      for (int n = 0; n < 4; ++n) {
        int col = cbase + n * 16 + lr;
        atomicAdd(&Lb[row * 128 + col], acc[m][n][r]);
      }
    }
}

// ---------------- softmax rows of L -> attnT bf16 [bh][f][g] ----------------
__global__ __launch_bounds__(256) void softmax_attnT(const float* __restrict__ L, u16* __restrict__ attnT) {
  const float scale = 0.08838834764831845f;  // 1/sqrt(128)
  int row = blockIdx.x * 4 + (threadIdx.x >> 6);  // 0..2047 = bh*128+g
  int l = threadIdx.x & 63;
  const float* p = L + (long)row * 128;
  float v0 = p[l] * scale, v1 = p[l + 64] * scale;
  float m = fmaxf(v0, v1);
  for (int off = 32; off; off >>= 1) m = fmaxf(m, __shfl_xor(m, off));
  float e0 = __expf(v0 - m), e1 = __expf(v1 - m);
  float s = e0 + e1;
  for (int off = 32; off; off >>= 1) s += __shfl_xor(s, off);
  float inv = 1.f / s;
  int bh = row >> 7, g = row & 127;
  u16* at = attnT + (long)bh * 16384 + g;
  at[(long)l * 128] = f2bf(e0 * inv);
  at[(long)(l + 64) * 128] = f2bf(e1 * inv);
}

// ---------------- b2[b][o] = bo[o] + sum Weff[b][o][c']*bv[c'] ----------------
__global__ __launch_bounds__(256) void b2_k(const u16* __restrict__ Weff, const float* __restrict__ bv,
                                            const float* __restrict__ bo, float* __restrict__ b2) {
  int idx = blockIdx.x * 256 + threadIdx.x;  // < 2048
  int b = idx >> 9, o = idx & 511;
  const u16* w = Weff + ((long)b * 512 + o) * 512;
  float s = bo[o];
  for (int c = 0; c < 512; ++c) s += bf2f(w[c]) * bv[c];
  b2[idx] = s;
}

// ---------------- IQBN stats per (c,qq) over (b,h,w) ----------------
__global__ __launch_bounds__(256) void stats_k(const u16* __restrict__ o2, float* __restrict__ stat) {
  const int g0 = blockIdx.x;  // 0..2047
  const int c = g0 >> 2, qq = g0 & 3;
  const int t = threadIdx.x;
  float s1 = 0.f, s2 = 0.f;
#pragma unroll
  for (int b = 0; b < 4; ++b) {
    const u16* p = o2 + ((long)(b * 512 + c) * 16384) + qq * 4096;
#pragma unroll
    for (int j = 0; j < 2; ++j) {
      uint4 v = *reinterpret_cast<const uint4*>(p + (t + j * 256) * 8);
      const unsigned int* pv = reinterpret_cast<const unsigned int*>(&v);
#pragma unroll
      for (int e = 0; e < 4; ++e) {
        float f0 = bf2f(pv[e] & 0xffffu);
        float f1 = bf2f(pv[e] >> 16);
        s1 += f0 + f1;
        s2 += f0 * f0 + f1 * f1;
      }
    }
  }
  for (int off = 32; off; off >>= 1) { s1 += __shfl_xor(s1, off); s2 += __shfl_xor(s2, off); }
  __shared__ float r1[4], r2[4];
  if ((t & 63) == 0) { r1[t >> 6] = s1; r2[t >> 6] = s2; }
  __syncthreads();
  if (t == 0) {
    float S1 = r1[0] + r1[1] + r1[2] + r1[3];
    float S2 = r2[0] + r2[1] + r2[2] + r2[3];
    float mean = S1 * (1.f / 16384.f);
    float var = S2 * (1.f / 16384.f) - mean * mean;
    stat[g0 * 2] = mean;
    stat[g0 * 2 + 1] = 1.f / sqrtf(var + 1e-5f);
  }
}

// ---------------- normalize -> fp32 out ----------------
__global__ __launch_bounds__(256) void norm_k(const u16* __restrict__ o2, const float* __restrict__ stat,
                                              const float* __restrict__ gamma, const float* __restrict__ beta,
                                              float* __restrict__ out) {
  long i8 = ((long)blockIdx.x * 256 + threadIdx.x) * 8;
  int c = (int)((i8 >> 14) & 511);
  int s = (int)(i8 & 16383);
  int g0 = c * 4 + (s >> 12);
  float mean = stat[g0 * 2], inv = stat[g0 * 2 + 1];
  float sc = inv * gamma[c];
  float sh = beta[c] - mean * sc;
  uint4 v = *reinterpret_cast<const uint4*>(o2 + i8);
  const unsigned int* pv = reinterpret_cast<const unsigned int*>(&v);
  float4 ra, rb;
  ra.x = bf2f(pv[0] & 0xffffu) * sc + sh; ra.y = bf2f(pv[0] >> 16) * sc + sh;
  ra.z = bf2f(pv[1] & 0xffffu) * sc + sh; ra.w = bf2f(pv[1] >> 16) * sc + sh;
  rb.x = bf2f(pv[2] & 0xffffu) * sc + sh; rb.y = bf2f(pv[2] >> 16) * sc + sh;
  rb.z = bf2f(pv[3] & 0xffffu) * sc + sh; rb.w = bf2f(pv[3] >> 16) * sc + sh;
  *reinterpret_cast<float4*>(out + i8) = ra;
  *reinterpret_cast<float4*>(out + i8 + 4) = rb;
}

extern "C" void kernel_launch(void* const* d_in, const int* in_sizes, int n_in,
                              void* d_out, int out_size, void* d_ws, size_t ws_size,
                              hipStream_t stream) {
  const float* x1 = (const float*)d_in[0];
  const float* x2 = (const float*)d_in[1];
  const float* Wq = (const float*)d_in[2];
  const float* bq = (const float*)d_in[3];
  const float* Wk = (const float*)d_in[4];
  const float* bk = (const float*)d_in[5];
  const float* Wv = (const float*)d_in[6];
  const float* bv = (const float*)d_in[7];
  const float* Wa1 = (const float*)d_in[8];
  const float* ba1 = (const float*)d_in[9];
  const float* Wa2 = (const float*)d_in[10];
  const float* ba2 = (const float*)d_in[11];
  const float* Wo = (const float*)d_in[12];
  const float* bo = (const float*)d_in[13];
  const float* gamma = (const float*)d_in[14];
  const float* beta = (const float*)d_in[15];
  float* out = (float*)d_out;

  char* ws = (char*)d_ws;
  const long MB = 1024L * 1024L;
  u16* X1T = (u16*)(ws);                        // 64MB  bf16 [B][S][C]  (later reused as O2)
  u16* X2T = (u16*)(ws + 64 * MB);              // 64MB
  u16* Qb  = (u16*)(ws + 128 * MB);             // 64MB  bf16 [B][C][S]
  u16* Kb  = (u16*)(ws + 192 * MB);             // 64MB
  float* AW = (float*)(ws + 256 * MB);          // 1MB   [B][4][S]
  float* L  = (float*)(ws + 257 * MB);          // 1MB   [16][128][128]
  u16* ATT  = (u16*)(ws + 258 * MB);            // 0.5MB [16][f][g]
  u16* WEFF = (u16*)(ws + 259 * MB);            // 2MB   [B][512][512]
  u16* W2   = (u16*)(ws + 261 * MB);            // 2MB
  u16* WQB  = (u16*)(ws + 263 * MB);            // 0.5MB
  u16* WKB  = (u16*)(ws + 263 * MB + 512 * 1024);
  u16* WA1B = (u16*)(ws + 264 * MB);            // 128KB
  u16* WVT  = (u16*)(ws + 264 * MB + 256 * 1024);  // 0.5MB (Wv transposed)
  u16* WOH  = (u16*)(ws + 264 * MB + 768 * 1024);  // 0.5MB [h][o][g]
  float* B2 = (float*)(ws + 265 * MB + 256 * 1024);  // 8KB
  float* STAT = (float*)(ws + 265 * MB + 512 * 1024);  // 16KB
  u16* O2 = X1T;
  (void)ws_size; (void)in_sizes; (void)n_in; (void)out_size;

  dim3 blk(256);
  const long SC = (long)16384 * 512;

  // converts / transposes
  cvt_k<<<dim3(256), blk, 0, stream>>>(Wq, WQB, 65536);
  cvt_k<<<dim3(256), blk, 0, stream>>>(Wk, WKB, 65536);
  cvt_k<<<dim3(64), blk, 0, stream>>>(Wa1, WA1B, 16384);
  transpose_cvt<<<dim3(256, 8, 4), blk, 0, stream>>>(x1, X1T, 512, 16384, SC, SC);
  transpose_cvt<<<dim3(256, 8, 4), blk, 0, stream>>>(x2, X2T, 512, 16384, SC, SC);
  transpose_cvt<<<dim3(8, 8, 1), blk, 0, stream>>>(Wv, WVT, 512, 512, 0, 0);
  woh_k<<<dim3(1024), blk, 0, stream>>>(Wo, WOH);

  // gate weights aw
  gemm_a1_aw<<<dim3(128, 1, 4), blk, 0, stream>>>(WA1B, X1T, ba1, Wa2, ba2, AW);

  // q, k (gated)
  gemm_bt<MODE_GATE><<<dim3(128, 4, 4), blk, 0, stream>>>(WQB, X1T, Qb, bq, AW, 512, 16384, 512, 0L, SC, SC);
  gemm_bt<MODE_GATE><<<dim3(128, 4, 4), blk, 0, stream>>>(WKB, X2T, Kb, bk, AW, 512, 16384, 512, 0L, SC, SC);

  // logits + softmax
  hipMemsetAsync(L, 0, 16 * 128 * 128 * sizeof(float), stream);
  logits_k<<<dim3(8, 16), blk, 0, stream>>>(Qb, Kb, L);
  softmax_attnT<<<dim3(512), blk, 0, stream>>>(L, ATT);

  // folds: Weff, b2, W2
  gemm_bt<MODE_FOLD1><<<dim3(1, 4, 16), blk, 0, stream>>>(WOH, ATT, WEFF, nullptr, nullptr, 512, 128, 128, 0L, 0L, 0L);
  b2_k<<<dim3(8), blk, 0, stream>>>(WEFF, bv, bo, B2);
  gemm_bt<MODE_PLAIN><<<dim3(4, 4, 4), blk, 0, stream>>>(WEFF, WVT, W2, nullptr, nullptr, 512, 512, 512,
                                                         512L * 512L, 0L, 512L * 512L);

  // o2 = W2[b] @ x2 + b2
  gemm_bt<MODE_BIAS><<<dim3(128, 4, 4), blk, 0, stream>>>(W2, X2T, O2, B2, nullptr, 512, 16384, 512,
                                                          512L * 512L, SC, SC);

  // IQBN
  stats_k<<<dim3(2048), blk, 0, stream>>>(O2, STAT);
  norm_k<<<dim3(16384), blk, 0, stream>>>(O2, STAT, gamma, beta, out);
}